// Round 21
// baseline (35.968 us; speedup 1.0000x reference)
//
#include <hip/hip_runtime.h>
#include <hip/hip_fp16.h>

// PatchMMD via fused im2col + MFMA patch-GEMM (R21).
//   D(i,j,p,q) = ||patch_i(p,q) - patch_j(p,q)||^2  (3x3 VALID -> 62x62)
//   K = exp(-D/40.5);  out = offmean(Kxx) - 2*mean(Kxy) + offmean(Kyy)
//
// Identity: D = pre_i + pre_j - 2*<patch_i,patch_j>. Stack 128 images; the
// per-position 128x128 Gram matrix is a K=9 GEMM -> mfma_f32_16x16x16f16,
// 8 diag + 28 strict-lower 16x16 tiles (symmetry); diag elems -> exp2(~0)=1,
// subtracted exactly at combine.
//
// R21 = R18 (best, 16.35us; phases A-D verbatim) + single-launch finish:
//   - 16-way spread ticket tree: block b -> atomicAdd(cnt1[b&15]) (62/line,
//     16 parallel lines), line-last -> atomicAdd(cnt2) (16 arrivals), overall
//     last block fences + reduces the 992 partials in-kernel.
//     (R13's 60us = 2976 same-ADDRESS fp64 CAS; R15's cost = 992 same-address
//     atomics + pins. Spread tree caps per-line serialization at 62.)
//   - fence/visibility pattern verbatim R15 (proven correct, absmax 0.0).
//   - 68B memset node zeroes counters each call (graph-legal).
//   Tests the "fixed launch/graph overhead" theory: saves one kernel node
//   + final-kernel exec; if dur doesn't drop, R18 structure is the floor.
// (R20's direct-global build REVERTED: uncoalesced per-image loads, -13%.)

typedef __attribute__((ext_vector_type(4))) _Float16 half4v;
typedef __attribute__((ext_vector_type(4))) float f32x4;

#define NPOS 3844        // 62*62
#define WSTR 26          // window n-stride in u16 (13 dwords, odd -> no conflicts)
#define RSTR 20          // record stride in u16 (40B: 8B-aligned, 16-bank pattern)
#define NBLK 992         // 62 * 16

#define W_OFF (1.0 / (64.0 * 63.0 * 62.0 * 62.0))   // per-set N*(N-1)*h*w
#define W_ALL (1.0 / (64.0 * 64.0 * 62.0 * 62.0))   // N*N*h*w

#if __has_builtin(__builtin_amdgcn_exp2f)
#define EXP2F(v) __builtin_amdgcn_exp2f(v)
#else
#define EXP2F(v) __expf((v) * 0.69314718055994530942f)
#endif

// ---------------- DPP helpers (validated R4..R18) ----------------
template<int CTRL>
__device__ __forceinline__ float dpp0_f(float v) {
    int r = __builtin_amdgcn_update_dpp(0, __float_as_int(v), CTRL, 0xf, 0xf, true);
    return __int_as_float(r);
}
template<int CTRL, int RM>
__device__ __forceinline__ float dppm_f(float v) {
    int r = __builtin_amdgcn_update_dpp(0, __float_as_int(v), CTRL, RM, 0xf, true);
    return __int_as_float(r);
}
__device__ __forceinline__ float wave_reduce_f(float v) {
    v += dpp0_f<0x111>(v);            // row_shr:1
    v += dpp0_f<0x112>(v);            // row_shr:2
    v += dpp0_f<0x114>(v);            // row_shr:4
    v += dpp0_f<0x118>(v);            // row_shr:8  -> lane 15 of each row
    v += dppm_f<0x142, 0xa>(v);       // bcast15 into rows 1,3
    v += dppm_f<0x143, 0xc>(v);       // bcast31 into rows 2,3 -> lane 63 total
    return v;
}
__device__ __forceinline__ unsigned short f16bits(float f) {
    __half h = __float2half(f);                  // RNE
    return *reinterpret_cast<unsigned short*>(&h);
}
__device__ __forceinline__ float f16tof(unsigned short u) {
    __half h = *reinterpret_cast<__half*>(&u);
    return __half2float(h);
}

// ---------------- fused kernel (single launch) ----------------
__global__ __launch_bounds__(256, 4) void mmd_fused_kernel(
    const float* __restrict__ x, const float* __restrict__ y,
    float* __restrict__ part, unsigned int* __restrict__ cnt1,
    unsigned int* __restrict__ cnt2, float* __restrict__ out)
{
    const int t = threadIdx.x, wid = t >> 6, lane = t & 63;
    const int p  = blockIdx.x >> 4;        // output row 0..61
    const int qg = blockIdx.x & 15;        // q-quad
    const int q  = qg * 4 + wid;           // this wave's position; valid iff < 62

    __shared__ unsigned short win[128 * WSTR];    // [n][u*8 + c] f16, c=0..7
    __shared__ unsigned short rec[4 * 128 * RSTR];// [ql][n][20] k=0..15 (>=9 zero)
    __shared__ float pren[4 * 128];               // [ql][n] NS * ||patch||^2
    __shared__ float wred[3][4];
    __shared__ double wfin[4];
    __shared__ int is_last;

    const float NS   = -1.0f / (40.5f * 0.69314718055994530942f);  // exp2 scale
    const float M2NS = -2.0f * NS;

    // ---- A: stage 12-col window (cols 4qg..4qg+7, 2nd group clamped) ----
    {
        const int cg1 = (qg < 15) ? qg + 1 : 15;   // clamp feeds only q>=62 waves
        #pragma unroll
        for (int k = 0; k < 3; ++k) {
            int it = t + k * 256;
            int n = it / 6, rem = it % 6;
            int u = rem >> 1, cg = rem & 1;
            const float* img = (n < 64) ? (x + n * 4096) : (y + (n - 64) * 4096);
            float4 v = *reinterpret_cast<const float4*>(
                img + (p + u) * 64 + ((cg ? cg1 : qg) << 2));
            unsigned int d0 = f16bits(v.x) | ((unsigned)f16bits(v.y) << 16);
            unsigned int d1 = f16bits(v.z) | ((unsigned)f16bits(v.w) << 16);
            unsigned int* w32 = reinterpret_cast<unsigned int*>(
                &win[n * WSTR + u * 8 + cg * 4]);
            w32[0] = d0; w32[1] = d1;
        }
    }
    __syncthreads();

    // ---- B: build records + pre, all lanes busy; 2 records per thread ----
    #pragma unroll
    for (int k = 0; k < 2; ++k) {
        int rid = t + k * 256;
        int ql = rid >> 7, n = rid & 127;
        const unsigned short* wp = &win[n * WSTR + ql];
        unsigned short b[9];
        #pragma unroll
        for (int u = 0; u < 3; ++u) {
            b[u * 3 + 0] = wp[u * 8 + 0];
            b[u * 3 + 1] = wp[u * 8 + 1];
            b[u * 3 + 2] = wp[u * 8 + 2];
        }
        float pre = 0.f;
        #pragma unroll
        for (int e = 0; e < 9; ++e) {
            float fv = f16tof(b[e]);
            pre = fmaf(fv, fv, pre);
        }
        unsigned short* dp = &rec[(size_t)rid * RSTR];
        uint2 s0, s1, s2, s3;
        s0.x = b[0] | ((unsigned)b[1] << 16);
        s0.y = b[2] | ((unsigned)b[3] << 16);
        s1.x = b[4] | ((unsigned)b[5] << 16);
        s1.y = b[6] | ((unsigned)b[7] << 16);
        s2.x = (unsigned)b[8]; s2.y = 0u;
        s3.x = 0u;             s3.y = 0u;
        *reinterpret_cast<uint2*>(dp)      = s0;   // k0..3
        *reinterpret_cast<uint2*>(dp + 4)  = s1;   // k4..7
        *reinterpret_cast<uint2*>(dp + 8)  = s2;   // k8,0,0,0
        *reinterpret_cast<uint2*>(dp + 12) = s3;   // k12..15 = 0 (kg=3 slice)
        pren[rid] = pre * NS;
    }
    __syncthreads();

    // ---- C: fragments + pre slices. 16x16x16 f16 lane layout:
    // row/col = lane&15, k = (lane>>4)*4 + e.  C/D: col=lane&15, row=kg*4+m.
    const int r = lane & 15, kg = lane >> 4;
    half4v frag[8];
    #pragma unroll
    for (int g = 0; g < 8; ++g)
        frag[g] = *reinterpret_cast<const half4v*>(
            &rec[(size_t)(wid * 128 + g * 16 + r) * RSTR + kg * 4]);

    float pa[8][4], pb[8];
    #pragma unroll
    for (int g = 0; g < 8; ++g) {
        const float* pp = &pren[wid * 128 + g * 16 + kg * 4];
        pa[g][0] = pp[0]; pa[g][1] = pp[1]; pa[g][2] = pp[2]; pa[g][3] = pp[3];
        pb[g] = pren[wid * 128 + g * 16 + r];
    }

    const f32x4 zf = {0.f, 0.f, 0.f, 0.f};
    float ad0 = 0.f, ad1 = 0.f, as0 = 0.f, as1 = 0.f, ac0 = 0.f, ac1 = 0.f;

    // ---- D: diag tiles, streamed (i==j elems -> exp2(~0)=1, removed later)
    #pragma unroll
    for (int g = 0; g < 8; ++g) {
        f32x4 c4 = __builtin_amdgcn_mfma_f32_16x16x16f16(frag[g], frag[g], zf, 0, 0, 0);
        float e = 0.f;
        #pragma unroll
        for (int m = 0; m < 4; ++m)
            e += EXP2F(fmaf(c4[m], M2NS, pa[g][m] + pb[g]));
        if (g & 1) ad1 += e; else ad0 += e;
    }

    // ---- 28 strict-lower tiles: same-half weight 2 at combine, cross 1 ----
    #pragma unroll
    for (int ti = 1; ti < 8; ++ti)
        #pragma unroll
        for (int tj = 0; tj < ti; ++tj) {
            f32x4 c4 = __builtin_amdgcn_mfma_f32_16x16x16f16(frag[ti], frag[tj], zf, 0, 0, 0);
            float e = 0.f;
            #pragma unroll
            for (int m = 0; m < 4; ++m)
                e += EXP2F(fmaf(c4[m], M2NS, pa[ti][m] + pb[tj]));
            if (ti >= 4 && tj < 4) { if (tj & 1) ac1 += e; else ac0 += e; }
            else                   { if (tj & 1) as1 += e; else as0 += e; }
        }

    float acc_diag  = wave_reduce_f(ad0 + ad1);
    float acc_same  = wave_reduce_f(as0 + as1);
    float acc_cross = wave_reduce_f(ac0 + ac1);
    if (lane == 63) {
        const bool valid = (q < 62);
        wred[0][wid] = valid ? acc_diag  : 0.f;
        wred[1][wid] = valid ? acc_same  : 0.f;
        wred[2][wid] = valid ? acc_cross : 0.f;
    }
    __syncthreads();

    // ---- E: per-block partial + release fence + 16-way ticket tree ----
    if (t == 0) {
        double sd = (double)((wred[0][0] + wred[0][1]) + (wred[0][2] + wred[0][3]));
        double ss = (double)((wred[1][0] + wred[1][1]) + (wred[1][2] + wred[1][3]));
        double sc = (double)((wred[2][0] + wred[2][1]) + (wred[2][2] + wred[2][3]));
        part[blockIdx.x] = (float)((sd + 2.0 * ss) * W_OFF - 2.0 * sc * W_ALL);
        __threadfence();                           // release: partial visible
        int last = 0;
        unsigned int l1 = atomicAdd(&cnt1[blockIdx.x & 15], 1u);
        if (l1 == 61u) {                           // last of this line's 62 blocks
            unsigned int l2 = atomicAdd(cnt2, 1u);
            last = (l2 == 15u);                    // last line overall
        }
        is_last = last;
    }
    __syncthreads();

    // ---- F: overall-last block reduces all 992 partials (fp64) ----
    if (is_last) {
        __threadfence();                           // acquire: see all partials
        double v = 0.0;
        #pragma unroll
        for (int k = 0; k < 4; ++k) {
            int e = t + k * 256;
            if (e < NBLK) v += (double)part[e];
        }
        #pragma unroll
        for (int off = 32; off > 0; off >>= 1)
            v += __shfl_xor(v, off);
        if (lane == 0) wfin[wid] = v;
        __syncthreads();
        if (t == 0) {
            double S = (wfin[0] + wfin[1]) + (wfin[2] + wfin[3]);
            out[0] = (float)(S - 128.0 * (double)NPOS * W_OFF);  // remove exact-1 diag
        }
    }
}

// ---------------- launch ----------------
extern "C" void kernel_launch(void* const* d_in, const int* in_sizes, int n_in,
                              void* d_out, int out_size, void* d_ws, size_t ws_size,
                              hipStream_t stream) {
    const float* x = (const float*)d_in[0];
    const float* y = (const float*)d_in[1];
    float* out  = (float*)d_out;
    float* part = (float*)d_ws;                                  // 992 floats
    unsigned int* cnt1 = (unsigned int*)((char*)d_ws + NBLK * 4);// 16 u32
    unsigned int* cnt2 = cnt1 + 16;                              // 1 u32

    (void)hipMemsetAsync(cnt1, 0, 17 * 4, stream);   // zero ticket tree (graph-legal)
    mmd_fused_kernel<<<NBLK, 256, 0, stream>>>(x, y, part, cnt1, cnt2, out);
}

// Round 22
// 16.285 us; speedup vs baseline: 2.2087x; 2.2087x over previous
//
#include <hip/hip_runtime.h>
#include <hip/hip_fp16.h>

// PatchMMD via fused im2col + MFMA patch-GEMM (R22).
//   D(i,j,p,q) = ||patch_i(p,q) - patch_j(p,q)||^2  (3x3 VALID -> 62x62)
//   K = exp(-D/40.5);  out = offmean(Kxx) - 2*mean(Kxy) + offmean(Kyy)
//
// Identity: D = pre_i + pre_j - 2*<patch_i,patch_j>. Stack 128 images; the
// per-position 128x128 Gram matrix is a K=9 GEMM -> mfma_f32_16x16x16f16,
// 8 diag + 28 strict-lower 16x16 tiles (symmetry); diag elems -> exp2(~0)=1,
// subtracted exactly at combine.
//
// R22 = R18 (best, 16.35us; A-D verbatim) + cross-quad pipelining:
//   each block runs TWO q-quads sequentially (grid 992->496). Quad-1's
//   global loads are ISSUED right after quad-0's fragment loads and their
//   latency hides under quad-0's MFMA+exp2 phase; the cvt+LDS-write lands
//   after (T14 issue-early/write-late). Removes one serial stage phase per
//   2 quads + halves per-block fixed overhead. win double-buffered
//   (LDS ~36.2 KB, still 4 blocks/CU); rec/pren reused across quads
//   (B(1) writes only after the post-D barrier).
// (R21 lesson: hipMemsetAsync graph node alone costs ~20us -> no memset,
//  no single-launch rendezvous; two plain kernels stay.)

typedef __attribute__((ext_vector_type(4))) _Float16 half4v;
typedef __attribute__((ext_vector_type(4))) float f32x4;

#define NPOS 3844        // 62*62
#define WSTR 26          // window n-stride in u16 (13 dwords, odd -> no conflicts)
#define RSTR 20          // record stride in u16 (40B: 8B-aligned, 16-bank pattern)
#define NBLK 496         // 62 * 8 (two quads per block)

#define W_OFF (1.0 / (64.0 * 63.0 * 62.0 * 62.0))   // per-set N*(N-1)*h*w
#define W_ALL (1.0 / (64.0 * 64.0 * 62.0 * 62.0))   // N*N*h*w

#if __has_builtin(__builtin_amdgcn_exp2f)
#define EXP2F(v) __builtin_amdgcn_exp2f(v)
#else
#define EXP2F(v) __expf((v) * 0.69314718055994530942f)
#endif

// ---------------- DPP helpers (validated R4..R18) ----------------
template<int CTRL>
__device__ __forceinline__ float dpp0_f(float v) {
    int r = __builtin_amdgcn_update_dpp(0, __float_as_int(v), CTRL, 0xf, 0xf, true);
    return __int_as_float(r);
}
template<int CTRL, int RM>
__device__ __forceinline__ float dppm_f(float v) {
    int r = __builtin_amdgcn_update_dpp(0, __float_as_int(v), CTRL, RM, 0xf, true);
    return __int_as_float(r);
}
__device__ __forceinline__ float wave_reduce_f(float v) {
    v += dpp0_f<0x111>(v);            // row_shr:1
    v += dpp0_f<0x112>(v);            // row_shr:2
    v += dpp0_f<0x114>(v);            // row_shr:4
    v += dpp0_f<0x118>(v);            // row_shr:8  -> lane 15 of each row
    v += dppm_f<0x142, 0xa>(v);       // bcast15 into rows 1,3
    v += dppm_f<0x143, 0xc>(v);       // bcast31 into rows 2,3 -> lane 63 total
    return v;
}
__device__ __forceinline__ unsigned short f16bits(float f) {
    __half h = __float2half(f);                  // RNE
    return *reinterpret_cast<unsigned short*>(&h);
}
__device__ __forceinline__ float f16tof(unsigned short u) {
    __half h = *reinterpret_cast<__half*>(&u);
    return __half2float(h);
}

// ---------------- fused kernel: 2 quads per block, pipelined ----------------
__global__ __launch_bounds__(256, 4) void mmd_fused_kernel(
    const float* __restrict__ x, const float* __restrict__ y,
    float* __restrict__ part)
{
    const int t = threadIdx.x, wid = t >> 6, lane = t & 63;
    const int p    = blockIdx.x >> 3;      // output row 0..61
    const int pair = blockIdx.x & 7;
    const int qg0  = pair * 2;             // quads qg0, qg0+1

    __shared__ unsigned short win[2][128 * WSTR]; // dbuf: [n][u*8 + c] f16
    __shared__ unsigned short rec[4 * 128 * RSTR];// [ql][n][20] (reused per quad)
    __shared__ float pren[4 * 128];               // [ql][n] NS * ||patch||^2
    __shared__ float wred[3][4];

    const float NS   = -1.0f / (40.5f * 0.69314718055994530942f);  // exp2 scale
    const float M2NS = -2.0f * NS;

    // staging-unit decomposition (same for every stage call)
    const int sn  = t % 128;               // not used for stage; see below
    (void)sn;

    // per-thread staging coords: 768 units = [n 0..127][u 0..2][cg 0..1]
    int s_n[3], s_u[3], s_cg[3];
    #pragma unroll
    for (int k = 0; k < 3; ++k) {
        int it = t + k * 256;
        s_n[k] = it / 6;
        int rem = it % 6;
        s_u[k]  = rem >> 1;
        s_cg[k] = rem & 1;
    }
    const float* imgs[3];
    #pragma unroll
    for (int k = 0; k < 3; ++k)
        imgs[k] = (s_n[k] < 64) ? (x + s_n[k] * 4096) : (y + (s_n[k] - 64) * 4096);

    // ---- A(0): stage win[0] for qg0 ----
    {
        const int cg1 = qg0 + 1;           // qg0 <= 14, so qg0+1 <= 15: no clamp
        #pragma unroll
        for (int k = 0; k < 3; ++k) {
            float4 v = *reinterpret_cast<const float4*>(
                imgs[k] + (p + s_u[k]) * 64 + ((s_cg[k] ? cg1 : qg0) << 2));
            unsigned int d0 = f16bits(v.x) | ((unsigned)f16bits(v.y) << 16);
            unsigned int d1 = f16bits(v.z) | ((unsigned)f16bits(v.w) << 16);
            unsigned int* w32 = reinterpret_cast<unsigned int*>(
                &win[0][s_n[k] * WSTR + s_u[k] * 8 + s_cg[k] * 4]);
            w32[0] = d0; w32[1] = d1;
        }
    }
    __syncthreads();

    float ad_t = 0.f, as_t = 0.f, ac_t = 0.f;   // across-quad accumulators
    const int r = lane & 15, kg = lane >> 4;

    #pragma unroll
    for (int quad = 0; quad < 2; ++quad) {
        const int qg = qg0 + quad;
        const int q  = qg * 4 + wid;       // valid iff < 62

        // ---- B: build records + pre from win[quad]; 2 records/thread ----
        #pragma unroll
        for (int k = 0; k < 2; ++k) {
            int rid = t + k * 256;
            int ql = rid >> 7, n = rid & 127;
            const unsigned short* wp = &win[quad][n * WSTR + ql];
            unsigned short b[9];
            #pragma unroll
            for (int u = 0; u < 3; ++u) {
                b[u * 3 + 0] = wp[u * 8 + 0];
                b[u * 3 + 1] = wp[u * 8 + 1];
                b[u * 3 + 2] = wp[u * 8 + 2];
            }
            float pre = 0.f;
            #pragma unroll
            for (int e = 0; e < 9; ++e) {
                float fv = f16tof(b[e]);
                pre = fmaf(fv, fv, pre);
            }
            unsigned short* dp = &rec[(size_t)rid * RSTR];
            uint2 s0, s1, s2, s3;
            s0.x = b[0] | ((unsigned)b[1] << 16);
            s0.y = b[2] | ((unsigned)b[3] << 16);
            s1.x = b[4] | ((unsigned)b[5] << 16);
            s1.y = b[6] | ((unsigned)b[7] << 16);
            s2.x = (unsigned)b[8]; s2.y = 0u;
            s3.x = 0u;             s3.y = 0u;
            *reinterpret_cast<uint2*>(dp)      = s0;   // k0..3
            *reinterpret_cast<uint2*>(dp + 4)  = s1;   // k4..7
            *reinterpret_cast<uint2*>(dp + 8)  = s2;   // k8,0,0,0
            *reinterpret_cast<uint2*>(dp + 12) = s3;   // k12..15 = 0
            pren[rid] = pre * NS;
        }
        __syncthreads();

        // ---- C: fragments + pre slices ----
        half4v frag[8];
        #pragma unroll
        for (int g = 0; g < 8; ++g)
            frag[g] = *reinterpret_cast<const half4v*>(
                &rec[(size_t)(wid * 128 + g * 16 + r) * RSTR + kg * 4]);

        float pa[8][4], pb[8];
        #pragma unroll
        for (int g = 0; g < 8; ++g) {
            const float* pp = &pren[wid * 128 + g * 16 + kg * 4];
            pa[g][0] = pp[0]; pa[g][1] = pp[1]; pa[g][2] = pp[2]; pa[g][3] = pp[3];
            pb[g] = pren[wid * 128 + g * 16 + r];
        }

        // ---- A(1) issue-early: quad 1's global loads start here, their
        // latency hides under this quad's MFMA+exp2 phase (quad 0 only) ----
        float4 pf[3];
        if (quad == 0) {
            const int cg1 = qg0 + 2;       // cols for qg0+1; <= 16? qg0<=14 -> cg1<=16
            const int cg1c = (cg1 < 16) ? cg1 : 15;   // clamp last group
            #pragma unroll
            for (int k = 0; k < 3; ++k)
                pf[k] = *reinterpret_cast<const float4*>(
                    imgs[k] + (p + s_u[k]) * 64 + ((s_cg[k] ? cg1c : (qg0 + 1)) << 2));
        }

        // ---- D: diag tiles streamed + 28 strict-lower tiles ----
        const f32x4 zf = {0.f, 0.f, 0.f, 0.f};
        float ad0 = 0.f, ad1 = 0.f, as0 = 0.f, as1 = 0.f, ac0 = 0.f, ac1 = 0.f;

        #pragma unroll
        for (int g = 0; g < 8; ++g) {
            f32x4 c4 = __builtin_amdgcn_mfma_f32_16x16x16f16(frag[g], frag[g], zf, 0, 0, 0);
            float e = 0.f;
            #pragma unroll
            for (int m = 0; m < 4; ++m)
                e += EXP2F(fmaf(c4[m], M2NS, pa[g][m] + pb[g]));
            if (g & 1) ad1 += e; else ad0 += e;
        }
        #pragma unroll
        for (int ti = 1; ti < 8; ++ti)
            #pragma unroll
            for (int tj = 0; tj < ti; ++tj) {
                f32x4 c4 = __builtin_amdgcn_mfma_f32_16x16x16f16(frag[ti], frag[tj], zf, 0, 0, 0);
                float e = 0.f;
                #pragma unroll
                for (int m = 0; m < 4; ++m)
                    e += EXP2F(fmaf(c4[m], M2NS, pa[ti][m] + pb[tj]));
                if (ti >= 4 && tj < 4) { if (tj & 1) ac1 += e; else ac0 += e; }
                else                   { if (tj & 1) as1 += e; else as0 += e; }
            }

        if (q < 62) {                      // wave-uniform validity
            ad_t += ad0 + ad1;
            as_t += as0 + as1;
            ac_t += ac0 + ac1;
        }

        // ---- A(1) write-late: cvt + store win[1] (vmcnt satisfied by D) ----
        if (quad == 0) {
            #pragma unroll
            for (int k = 0; k < 3; ++k) {
                unsigned int d0 = f16bits(pf[k].x) | ((unsigned)f16bits(pf[k].y) << 16);
                unsigned int d1 = f16bits(pf[k].z) | ((unsigned)f16bits(pf[k].w) << 16);
                unsigned int* w32 = reinterpret_cast<unsigned int*>(
                    &win[1][s_n[k] * WSTR + s_u[k] * 8 + s_cg[k] * 4]);
                w32[0] = d0; w32[1] = d1;
            }
        }
        __syncthreads();   // win[1] ready AND rec free for next B
    }

    float acc_diag  = wave_reduce_f(ad_t);
    float acc_same  = wave_reduce_f(as_t);
    float acc_cross = wave_reduce_f(ac_t);
    if (lane == 63) {
        wred[0][wid] = acc_diag;
        wred[1][wid] = acc_same;
        wred[2][wid] = acc_cross;
    }
    __syncthreads();
    if (t == 0) {
        double sd = (double)((wred[0][0] + wred[0][1]) + (wred[0][2] + wred[0][3]));
        double ss = (double)((wred[1][0] + wred[1][1]) + (wred[1][2] + wred[1][3]));
        double sc = (double)((wred[2][0] + wred[2][1]) + (wred[2][2] + wred[2][3]));
        part[blockIdx.x] = (float)((sd + 2.0 * ss) * W_OFF - 2.0 * sc * W_ALL);
    }
}

// ---------------- slim fp64 combine ----------------
__global__ __launch_bounds__(512) void mmd_final_kernel(
    const float* __restrict__ part, float* __restrict__ out)
{
    const int t = threadIdx.x;
    double v = (t < NBLK) ? (double)part[t] : 0.0;
    #pragma unroll
    for (int off = 32; off > 0; off >>= 1)
        v += __shfl_xor(v, off);
    __shared__ double w[8];
    const int lane = t & 63, wd = t >> 6;
    if (lane == 0) w[wd] = v;
    __syncthreads();
    if (t == 0) {
        double S = 0.0;
        #pragma unroll
        for (int k = 0; k < 8; ++k) S += w[k];
        out[0] = (float)(S - 128.0 * (double)NPOS * W_OFF);  // remove exact-1 diagonal
    }
}

// ---------------- launch ----------------
extern "C" void kernel_launch(void* const* d_in, const int* in_sizes, int n_in,
                              void* d_out, int out_size, void* d_ws, size_t ws_size,
                              hipStream_t stream) {
    const float* x = (const float*)d_in[0];
    const float* y = (const float*)d_in[1];
    float* out  = (float*)d_out;
    float* part = (float*)d_ws;   // 496 floats = 2 KiB

    mmd_fused_kernel<<<NBLK, 256, 0, stream>>>(x, y, part);
    mmd_final_kernel<<<1, 512, 0, stream>>>(part, out);
}